// Round 1
// baseline (139.805 us; speedup 1.0000x reference)
//
#include <hip/hip_runtime.h>

// Problem constants
#define NBS   32        // BS*2 "half" groups: fea is [32][100][512]
#define XDIM  100       // HK*BAG
#define DDIM  512
#define HDIM  512
#define NT    512       // num_top
// ws layout (bytes)
#define WS_WT 0         // _Float16 Wt[2][512][512]            = 1,048,576 B
#define WS_H  1048576   // float    h[32][100][512]            = 6,553,600 B
#define WS_FP 7602176   // float    fp[2][16][100][100]        = 1,280,000 B

typedef _Float16 half8 __attribute__((ext_vector_type(8)));
typedef float floatx4 __attribute__((ext_vector_type(4)));

// ---------------------------------------------------------------------------
// Prep: W0,W1 (fp32 [d][c]) -> Wt (fp16, transposed [w][c][d])
__global__ void prep_w(const float* __restrict__ W0, const float* __restrict__ W1,
                       _Float16* __restrict__ Wt) {
    int o = blockIdx.x * 256 + threadIdx.x;          // 2*512*512 = 524288 total
    int w = o >> 18;
    int rem = o & 262143;
    int c = rem >> 9;
    int d = rem & 511;
    const float* W = w ? W1 : W0;
    Wt[o] = (_Float16)W[d * 512 + c];
}

// ---------------------------------------------------------------------------
// GEMM: h[bs][m][c] = sum_d fea[bs][m][d] * W{s}[d][c]  (+bias if s==1)
// One wave computes a 16x64 output tile via 4 MFMA accumulators.
__global__ void __launch_bounds__(256) gemm_k(const float* __restrict__ fea,
                                              const _Float16* __restrict__ Wt,
                                              const float* __restrict__ bias,
                                              float* __restrict__ h) {
    int bx   = blockIdx.x;          // 448 = 32 bs * 7 rowtiles * 2 colhalves
    int bs   = bx / 14;
    int rem  = bx % 14;
    int rt   = rem >> 1;            // 0..6 (rows of 16, covers 100 w/ guard)
    int chal = rem & 1;             // which 256-col half
    int w    = threadIdx.x >> 6;
    int lane = threadIdx.x & 63;
    int cg   = chal * 4 + w;        // 0..7 col-group of 64
    int n0   = cg * 64;
    int m0   = rt * 16;
    int s    = bs & 1;
    int l15  = lane & 15;
    int q    = lane >> 4;

    const float* arow = fea + (size_t)bs * (XDIM * DDIM)
                        + (size_t)min(m0 + l15, XDIM - 1) * DDIM + q * 8;
    const _Float16* bbase = Wt + (size_t)s * (HDIM * DDIM) + q * 8;
    const _Float16* b0p = bbase + (size_t)(n0 +  0 + l15) * DDIM;
    const _Float16* b1p = bbase + (size_t)(n0 + 16 + l15) * DDIM;
    const _Float16* b2p = bbase + (size_t)(n0 + 32 + l15) * DDIM;
    const _Float16* b3p = bbase + (size_t)(n0 + 48 + l15) * DDIM;

    floatx4 acc0 = {0.f, 0.f, 0.f, 0.f};
    floatx4 acc1 = acc0, acc2 = acc0, acc3 = acc0;

    for (int k = 0; k < DDIM; k += 32) {
        float4 a0 = *(const float4*)(arow + k);
        float4 a1 = *(const float4*)(arow + k + 4);
        half8 af;
        af[0] = (_Float16)a0.x; af[1] = (_Float16)a0.y;
        af[2] = (_Float16)a0.z; af[3] = (_Float16)a0.w;
        af[4] = (_Float16)a1.x; af[5] = (_Float16)a1.y;
        af[6] = (_Float16)a1.z; af[7] = (_Float16)a1.w;
        half8 bf0 = *(const half8*)(b0p + k);
        half8 bf1 = *(const half8*)(b1p + k);
        half8 bf2 = *(const half8*)(b2p + k);
        half8 bf3 = *(const half8*)(b3p + k);
        acc0 = __builtin_amdgcn_mfma_f32_16x16x32_f16(af, bf0, acc0, 0, 0, 0);
        acc1 = __builtin_amdgcn_mfma_f32_16x16x32_f16(af, bf1, acc1, 0, 0, 0);
        acc2 = __builtin_amdgcn_mfma_f32_16x16x32_f16(af, bf2, acc2, 0, 0, 0);
        acc3 = __builtin_amdgcn_mfma_f32_16x16x32_f16(af, bf3, acc3, 0, 0, 0);
    }

    // C/D layout: col = lane&15, row = (lane>>4)*4 + r
    float* hb = h + (size_t)bs * (XDIM * HDIM);
    #pragma unroll
    for (int j = 0; j < 4; ++j) {
        floatx4 a = (j == 0) ? acc0 : (j == 1) ? acc1 : (j == 2) ? acc2 : acc3;
        int col = n0 + 16 * j + l15;
        float bi = s ? bias[col] : 0.f;
        #pragma unroll
        for (int r = 0; r < 4; ++r) {
            int m = m0 + q * 4 + r;
            if (m < XDIM) hb[(size_t)m * HDIM + col] = a[r] + bi;
        }
    }
}

// ---------------------------------------------------------------------------
// full[b][x][y] = sum_h relu(h0[b][x][h] + h1'[b][y][h]) * v[h], k-split 2
__global__ void __launch_bounds__(256) full_k(const float* __restrict__ h,
                                              const float* __restrict__ v,
                                              float* __restrict__ fp) {
    int bx = blockIdx.x;        // 512 = 2 ksplit * 16 b * 4 xt * 4 yt
    int ks = bx >> 8;
    int rem = bx & 255;
    int b  = rem >> 4;
    int xt = (rem >> 2) & 3;
    int yt = rem & 3;
    int x0 = xt * 32, y0 = yt * 32;

    __shared__ float sh0[32][68];
    __shared__ float sh1[32][68];
    __shared__ float sv[64];

    int t  = threadIdx.x;
    int lx = (t >> 4) * 2;
    int ly = (t & 15) * 2;
    float acc00 = 0.f, acc01 = 0.f, acc10 = 0.f, acc11 = 0.f;

    const float* h0b = h + (size_t)(b * 2 + 0) * (XDIM * HDIM);
    const float* h1b = h + (size_t)(b * 2 + 1) * (XDIM * HDIM);

    for (int c = 0; c < 4; ++c) {
        int kc = ks * 256 + c * 64;
        if (c) __syncthreads();
        #pragma unroll
        for (int i = 0; i < 2; ++i) {
            int f = t + i * 256;              // 512 float4 slots per buffer
            int row = f >> 4, qq = f & 15;
            int gx = min(x0 + row, XDIM - 1);
            int gy = min(y0 + row, XDIM - 1);
            *(float4*)&sh0[row][qq * 4] = *(const float4*)(h0b + (size_t)gx * HDIM + kc + qq * 4);
            *(float4*)&sh1[row][qq * 4] = *(const float4*)(h1b + (size_t)gy * HDIM + kc + qq * 4);
        }
        if (t < 16) *(float4*)&sv[t * 4] = *(const float4*)(v + kc + t * 4);
        __syncthreads();

        for (int k = 0; k < 64; k += 4) {
            float4 a0 = *(const float4*)&sh0[lx][k];
            float4 a1 = *(const float4*)&sh0[lx + 1][k];
            float4 b0 = *(const float4*)&sh1[ly][k];
            float4 b1 = *(const float4*)&sh1[ly + 1][k];
            float4 vv = *(const float4*)&sv[k];
            const float* pa0 = (const float*)&a0;
            const float* pa1 = (const float*)&a1;
            const float* pb0 = (const float*)&b0;
            const float* pb1 = (const float*)&b1;
            const float* pv  = (const float*)&vv;
            #pragma unroll
            for (int j = 0; j < 4; ++j) {
                float vj = pv[j];
                acc00 += fmaxf(pa0[j] + pb0[j], 0.f) * vj;
                acc01 += fmaxf(pa0[j] + pb1[j], 0.f) * vj;
                acc10 += fmaxf(pa1[j] + pb0[j], 0.f) * vj;
                acc11 += fmaxf(pa1[j] + pb1[j], 0.f) * vj;
            }
        }
    }

    float* out = fp + ((size_t)ks * 16 + b) * (XDIM * XDIM);
    int x = x0 + lx, y = y0 + ly;
    if (x < XDIM) {
        if (y     < XDIM) out[(size_t)x * XDIM + y    ] = acc00;
        if (y + 1 < XDIM) out[(size_t)x * XDIM + y + 1] = acc01;
    }
    if (x + 1 < XDIM) {
        if (y     < XDIM) out[(size_t)(x + 1) * XDIM + y    ] = acc10;
        if (y + 1 < XDIM) out[(size_t)(x + 1) * XDIM + y + 1] = acc11;
    }
}

// ---------------------------------------------------------------------------
// pooled[b][i][j] = sum_{p,q} full[b][ind0[b,i,p]+50p][ind1[b,j,q]+50q]
// + pairs meshgrid, both written to d_out.
__global__ void __launch_bounds__(256) score_k(const float* __restrict__ fp,
                                               const int* __restrict__ ind0,
                                               const int* __restrict__ ind1,
                                               float* __restrict__ out) {
    int bx = blockIdx.x;            // 256 = 16 b * 16 i-tiles
    int b  = bx >> 4;
    int i0 = (bx & 15) * 32;

    __shared__ float rowsum[32][100];
    __shared__ int c0s[NT], c1s[NT];
    __shared__ int a0s[32], a1s[32];

    int t = threadIdx.x;
    if (t < 32) {
        int2 ii = *(const int2*)(ind0 + ((size_t)b * NT + i0 + t) * 2);
        a0s[t] = ii.x;
        a1s[t] = ii.y + 50;
    }
    for (int j = t; j < NT; j += 256) {
        int2 jj = *(const int2*)(ind1 + ((size_t)b * NT + j) * 2);
        c0s[j] = jj.x;
        c1s[j] = jj.y + 50;
    }
    __syncthreads();

    const float* f0 = fp + (size_t)b * (XDIM * XDIM);
    const float* f1 = fp + (size_t)(16 + b) * (XDIM * XDIM);
    for (int idx = t; idx < 32 * 128; idx += 256) {
        int il = idx >> 7, y = idx & 127;
        if (y < XDIM) {
            int a0 = a0s[il], a1 = a1s[il];
            rowsum[il][y] = f0[a0 * XDIM + y] + f0[a1 * XDIM + y]
                          + f1[a0 * XDIM + y] + f1[a1 * XDIM + y];
        }
    }
    __syncthreads();

    float*  sout = out + (size_t)b * (NT * NT) + (size_t)i0 * NT;
    float2* pout = (float2*)(out + (size_t)16 * NT * NT
                             + (size_t)b * (NT * NT * 2) + (size_t)i0 * NT * 2);
    for (int o = t; o < 32 * NT; o += 256) {
        int il = o >> 9, j = o & 511;
        float sc = rowsum[il][c0s[j]] + rowsum[il][c1s[j]];
        sout[(size_t)il * NT + j] = sc;
        float2 pr;
        pr.x = (float)(i0 + il);
        pr.y = (float)j;
        pout[o] = pr;
    }
}

// ---------------------------------------------------------------------------
extern "C" void kernel_launch(void* const* d_in, const int* in_sizes, int n_in,
                              void* d_out, int out_size, void* d_ws, size_t ws_size,
                              hipStream_t stream) {
    const float* fea  = (const float*)d_in[0];
    const int*   ind0 = (const int*)d_in[1];
    const int*   ind1 = (const int*)d_in[2];
    const float* W0   = (const float*)d_in[3];
    const float* W1   = (const float*)d_in[4];
    const float* bias = (const float*)d_in[5];
    const float* v    = (const float*)d_in[6];
    float* out = (float*)d_out;
    char*  ws  = (char*)d_ws;

    _Float16* Wt = (_Float16*)(ws + WS_WT);
    float*    h  = (float*)(ws + WS_H);
    float*    fp = (float*)(ws + WS_FP);

    hipLaunchKernelGGL(prep_w,  dim3(2048), dim3(256), 0, stream, W0, W1, Wt);
    hipLaunchKernelGGL(gemm_k,  dim3(448),  dim3(256), 0, stream, fea, Wt, bias, h);
    hipLaunchKernelGGL(full_k,  dim3(512),  dim3(256), 0, stream, h, v, fp);
    hipLaunchKernelGGL(score_k, dim3(256),  dim3(256), 0, stream, fp, ind0, ind1, out);
}

// Round 2
// 122.036 us; speedup vs baseline: 1.1456x; 1.1456x over previous
//
#include <hip/hip_runtime.h>

// Problem constants
#define XDIM  100       // HK*BAG
#define DDIM  512
#define HDIM  512
#define NT    512
// ws layout (bytes)
#define WS_WT2   0          // fp16 Wt2[2][16][512][4][8]   = 1,048,576 B
#define WS_FEA16 1048576    // fp16 fea16[3200][512]        = 3,276,800 B
#define WS_V16   4325376    // fp16 v16[512]                = 1,024 B
#define WS_H16   4326400    // fp16 h16[3200][512]          = 3,276,800 B
#define WS_FP    7603200    // fp32 fp[8][16][100][100]     = 5,120,000 B

typedef _Float16 h16x8 __attribute__((ext_vector_type(8)));
typedef _Float16 h2    __attribute__((ext_vector_type(2)));
typedef float floatx4  __attribute__((ext_vector_type(4)));

union H8U { h16x8 v; h2 p[4]; unsigned u[4]; };

// ---------------------------------------------------------------------------
// prep: Wt2 (mfma-B-fragment-ordered fp16 weights), fea16, v16
__global__ void __launch_bounds__(256) prep_k(const float* __restrict__ W0,
                                              const float* __restrict__ W1,
                                              const float* __restrict__ fea,
                                              const float* __restrict__ v,
                                              _Float16* __restrict__ Wt2,
                                              _Float16* __restrict__ fea16,
                                              _Float16* __restrict__ v16) {
    int blk = blockIdx.x;
    int t = threadIdx.x;
    if (blk < 2048) {
        // Wt2[w][kb][c][q][8] = W[d=kb*32+q*8+j][c]
        int o  = blk * 256 + t;
        int w  = o >> 18;
        int kb = (o >> 14) & 15;
        int c  = (o >> 5) & 511;
        int qj = o & 31;
        int d  = kb * 32 + qj;
        const float* W = w ? W1 : W0;
        Wt2[o] = (_Float16)W[d * 512 + c];
    } else if (blk < 3648) {
        int tid = (blk - 2048) * 256 + t;    // 409600 threads, 4 elems each
        float4 x = *(const float4*)(fea + (size_t)tid * 4);
        _Float16 r[4] = {(_Float16)x.x, (_Float16)x.y, (_Float16)x.z, (_Float16)x.w};
        *(uint2*)(fea16 + (size_t)tid * 4) = *(const uint2*)r;
    } else {
        v16[t * 2]     = (_Float16)v[t * 2];
        v16[t * 2 + 1] = (_Float16)v[t * 2 + 1];
    }
}

// ---------------------------------------------------------------------------
// gemm: h16[hb][m][c] = sum_d fea16[hb][m][d] * W{s}[d][c] (+bias if s==1)
__global__ void __launch_bounds__(256) gemm_k(const _Float16* __restrict__ fea16,
                                              const _Float16* __restrict__ Wt2,
                                              const float* __restrict__ bias,
                                              _Float16* __restrict__ h16) {
    int bx   = blockIdx.x;          // 448 = 32 hb * 7 rowtiles * 2 colhalves
    int hb   = bx / 14;
    int rem  = bx % 14;
    int rt   = rem >> 1;
    int chal = rem & 1;
    int w    = threadIdx.x >> 6;
    int lane = threadIdx.x & 63;
    int n0   = (chal * 4 + w) * 64;
    int m0   = rt * 16;
    int s    = hb & 1;
    int l15  = lane & 15;
    int q    = lane >> 4;
    int m    = min(m0 + l15, XDIM - 1);

    const _Float16* ap = fea16 + (size_t)hb * (XDIM * DDIM) + (size_t)m * DDIM + q * 8;
    const _Float16* bp = Wt2 + (size_t)s * 262144 + (size_t)(n0 + l15) * 32 + q * 8;

    floatx4 acc0 = {0.f, 0.f, 0.f, 0.f};
    floatx4 acc1 = acc0, acc2 = acc0, acc3 = acc0;

    for (int kb = 0; kb < 16; ++kb) {
        h16x8 a = *(const h16x8*)(ap + kb * 32);
        const _Float16* bkb = bp + kb * 16384;
        h16x8 b0 = *(const h16x8*)(bkb);
        h16x8 b1 = *(const h16x8*)(bkb + 512);
        h16x8 b2 = *(const h16x8*)(bkb + 1024);
        h16x8 b3 = *(const h16x8*)(bkb + 1536);
        acc0 = __builtin_amdgcn_mfma_f32_16x16x32_f16(a, b0, acc0, 0, 0, 0);
        acc1 = __builtin_amdgcn_mfma_f32_16x16x32_f16(a, b1, acc1, 0, 0, 0);
        acc2 = __builtin_amdgcn_mfma_f32_16x16x32_f16(a, b2, acc2, 0, 0, 0);
        acc3 = __builtin_amdgcn_mfma_f32_16x16x32_f16(a, b3, acc3, 0, 0, 0);
    }

    _Float16* hob = h16 + (size_t)hb * (XDIM * HDIM);
    #pragma unroll
    for (int j = 0; j < 4; ++j) {
        floatx4 a = (j == 0) ? acc0 : (j == 1) ? acc1 : (j == 2) ? acc2 : acc3;
        int col = n0 + 16 * j + l15;
        float bi = s ? bias[col] : 0.f;
        #pragma unroll
        for (int r = 0; r < 4; ++r) {
            int mr = m0 + q * 4 + r;
            if (mr < XDIM) hob[(size_t)mr * HDIM + col] = (_Float16)(a[r] + bi);
        }
    }
}

// ---------------------------------------------------------------------------
// full: fp[ks][b][x][y] = sum_{h in chunk ks} relu(h0[x,h]+h1[y,h])*v[h]
// 64x64 tile / block, 4x4 per thread, packed fp16 + v_dot2. Also writes pairs.
__global__ void __launch_bounds__(256) full_k(const _Float16* __restrict__ h16,
                                              const _Float16* __restrict__ v16,
                                              float* __restrict__ fp,
                                              float2* __restrict__ pout) {
    int bx  = blockIdx.x;           // 512 = 8 ks * 16 b * 2 xt * 2 yt
    int ks  = bx >> 6;
    int rem = bx & 63;
    int b   = rem >> 2;
    int xt  = (rem >> 1) & 1;
    int yt  = rem & 1;
    int x0  = xt * 36;              // tiles [0,64) and [36,100): overlap writes same values
    int y0  = yt * 36;
    int kc  = ks * 64;

    __shared__ _Float16 sh0[64][72];      // [x][k], stride 72 fp16 (bank-safe)
    __shared__ unsigned sh1p[32][64];     // [kpair][y] packed h2
    __shared__ unsigned sv[32];           // v pairs

    int t = threadIdx.x;
    int r = t & 63, kseg = t >> 6;

    const _Float16* g0 = h16 + ((size_t)(b * 2) * XDIM + x0 + r) * HDIM + kc + kseg * 16;
    *(h16x8*)&sh0[r][kseg * 16]     = *(const h16x8*)g0;
    *(h16x8*)&sh0[r][kseg * 16 + 8] = *(const h16x8*)(g0 + 8);

    const _Float16* g1 = h16 + ((size_t)(b * 2 + 1) * XDIM + y0 + r) * HDIM + kc + kseg * 16;
    H8U u0, u1;
    u0.v = *(const h16x8*)g1;
    u1.v = *(const h16x8*)(g1 + 8);
    #pragma unroll
    for (int pp = 0; pp < 4; ++pp) {
        sh1p[kseg * 8 + pp][r]     = u0.u[pp];
        sh1p[kseg * 8 + 4 + pp][r] = u1.u[pp];
    }
    if (t < 32) sv[t] = *(const unsigned*)(v16 + kc + t * 2);
    __syncthreads();

    // pairs meshgrid: pure stores, drain under the compute below
    {
        size_t pbase = (size_t)bx * 8192;
        #pragma unroll 4
        for (int i = 0; i < 32; ++i) {
            unsigned idx = (unsigned)(pbase + i * 256 + t);
            float2 pr;
            pr.x = (float)((idx >> 9) & 511);
            pr.y = (float)(idx & 511);
            pout[idx] = pr;
        }
    }

    int ty = t >> 4, tx = t & 15;
    float acc[4][4] = {};
    h2 hz; hz[0] = (_Float16)0; hz[1] = (_Float16)0;

    for (int kk = 0; kk < 8; ++kk) {
        H8U a[4];
        #pragma unroll
        for (int i = 0; i < 4; ++i)
            a[i].v = *(const h16x8*)&sh0[ty * 4 + i][kk * 8];
        uint4 bq[4];
        #pragma unroll
        for (int p = 0; p < 4; ++p)
            bq[p] = *(const uint4*)&sh1p[kk * 4 + p][tx * 4];
        uint4 vq = *(const uint4*)&sv[kk * 4];
        const unsigned* vqa = (const unsigned*)&vq;

        #pragma unroll
        for (int p = 0; p < 4; ++p) {
            h2 vp = __builtin_bit_cast(h2, vqa[p]);
            const unsigned* bqa = (const unsigned*)&bq[p];
            #pragma unroll
            for (int i = 0; i < 4; ++i) {
                h2 av = a[i].p[p];
                #pragma unroll
                for (int j = 0; j < 4; ++j) {
                    h2 s = av + __builtin_bit_cast(h2, bqa[j]);
                    s = __builtin_elementwise_max(s, hz);
#if __has_builtin(__builtin_amdgcn_fdot2)
                    acc[i][j] = __builtin_amdgcn_fdot2(s, vp, acc[i][j], false);
#else
                    acc[i][j] += (float)s[0] * (float)vp[0] + (float)s[1] * (float)vp[1];
#endif
                }
            }
        }
    }

    float* fpb = fp + (size_t)(ks * 16 + b) * (XDIM * XDIM);
    #pragma unroll
    for (int i = 0; i < 4; ++i) {
        float4 o;
        o.x = acc[i][0]; o.y = acc[i][1]; o.z = acc[i][2]; o.w = acc[i][3];
        *(float4*)&fpb[(size_t)(x0 + ty * 4 + i) * XDIM + y0 + tx * 4] = o;
    }
}

// ---------------------------------------------------------------------------
// score: pooled[b][i][j] = sum_ks sum_{rows a0,a1} sum_{cols c0,c1} fp[...]
__global__ void __launch_bounds__(256) score_k(const float* __restrict__ fp,
                                               const int* __restrict__ ind0,
                                               const int* __restrict__ ind1,
                                               float* __restrict__ out) {
    int bx  = blockIdx.x;           // 512 = 16 b * 16 itiles * 2 jhalves
    int b   = bx >> 5;
    int rem = bx & 31;
    int it  = rem >> 1;
    int jh  = rem & 1;
    int i0  = it * 32;

    __shared__ float rowsum[32][100];
    __shared__ int a0s[32], a1s[32];
    __shared__ int c0s[256], c1s[256];

    int t = threadIdx.x;
    if (t < 32) {
        int2 ii = *(const int2*)(ind0 + ((size_t)b * NT + i0 + t) * 2);
        a0s[t] = ii.x;
        a1s[t] = ii.y + 50;
    }
    {
        int2 jj = *(const int2*)(ind1 + ((size_t)b * NT + jh * 256 + t) * 2);
        c0s[t] = jj.x;
        c1s[t] = jj.y + 50;
    }
    __syncthreads();

    const float* fb = fp + (size_t)b * (XDIM * XDIM);
    for (int idx = t; idx < 1024; idx += 256) {
        int il = idx >> 5, yq = idx & 31;
        if (yq < 25) {
            float4 s = {0.f, 0.f, 0.f, 0.f};
            int a0 = a0s[il] * XDIM + yq * 4;
            int a1 = a1s[il] * XDIM + yq * 4;
            #pragma unroll
            for (int ksb = 0; ksb < 8; ++ksb) {
                const float* pl = fb + (size_t)ksb * (16 * XDIM * XDIM);
                float4 u = *(const float4*)(pl + a0);
                float4 w = *(const float4*)(pl + a1);
                s.x += u.x + w.x; s.y += u.y + w.y;
                s.z += u.z + w.z; s.w += u.w + w.w;
            }
            *(float4*)&rowsum[il][yq * 4] = s;
        }
    }
    __syncthreads();

    float* sout = out + (size_t)b * (NT * NT) + (size_t)i0 * NT + jh * 256;
    for (int o = t; o < 8192; o += 256) {
        int il = o >> 8, jl = o & 255;
        sout[(size_t)il * NT + jl] = rowsum[il][c0s[jl]] + rowsum[il][c1s[jl]];
    }
}

// ---------------------------------------------------------------------------
extern "C" void kernel_launch(void* const* d_in, const int* in_sizes, int n_in,
                              void* d_out, int out_size, void* d_ws, size_t ws_size,
                              hipStream_t stream) {
    const float* fea  = (const float*)d_in[0];
    const int*   ind0 = (const int*)d_in[1];
    const int*   ind1 = (const int*)d_in[2];
    const float* W0   = (const float*)d_in[3];
    const float* W1   = (const float*)d_in[4];
    const float* bias = (const float*)d_in[5];
    const float* v    = (const float*)d_in[6];
    float* out = (float*)d_out;
    char*  ws  = (char*)d_ws;

    _Float16* Wt2   = (_Float16*)(ws + WS_WT2);
    _Float16* fea16 = (_Float16*)(ws + WS_FEA16);
    _Float16* v16   = (_Float16*)(ws + WS_V16);
    _Float16* h16   = (_Float16*)(ws + WS_H16);
    float*    fp    = (float*)(ws + WS_FP);
    float2*   pout  = (float2*)(out + (size_t)16 * NT * NT);

    hipLaunchKernelGGL(prep_k,  dim3(3649), dim3(256), 0, stream, W0, W1, fea, v, Wt2, fea16, v16);
    hipLaunchKernelGGL(gemm_k,  dim3(448),  dim3(256), 0, stream, fea16, Wt2, bias, h16);
    hipLaunchKernelGGL(full_k,  dim3(512),  dim3(256), 0, stream, h16, v16, fp, pout);
    hipLaunchKernelGGL(score_k, dim3(512),  dim3(256), 0, stream, fp, ind0, ind1, out);
}